// Round 8
// baseline (1093.308 us; speedup 1.0000x reference)
//
#include <hip/hip_runtime.h>
#include <hip/hip_fp16.h>

#define BB 512
#define TT 512
#define EE 100
#define HH 40
#define GG 120   // 3*HH
#define TC 32    // timesteps per chunk
#define NC 16    // chunks
#define NSCAN 128  // scan blocks (512 pairs / 4 waves)

typedef _Float16 h2_t __attribute__((ext_vector_type(2)));
union F4H { float4 f; h2_t h[4]; };

__device__ __forceinline__ float fdot2_(h2_t a, h2_t b, float c) {
    return __builtin_amdgcn_fdot2(a, b, c, false);
}
__device__ __forceinline__ h2_t pack2_(float x, float y) {
    h2_t r; r[0] = (_Float16)x; r[1] = (_Float16)y; return r;
}
__device__ __forceinline__ float sigmoid_(float x) {
    return 1.0f / (1.0f + __expf(-x));
}
__device__ __forceinline__ float tanhfast_(float x) {
    float e = __expf(2.0f * x);
    return 1.0f - 2.0f / (e + 1.0f);
}

// Fused: blocks [0,nScan) = scan chunk cs (reads gxR); rest = GEMM chunk cg
// (writes gxW). Disjoint data -> G16-safe.
//
// Scan (round-8 change): one wave = 2 SAME-DIR chains (batches bA,bB) so Whh
// is SHARED (60 VGPRs, the r5-proven-resident budget). Each wave STAGES its
// 2 chains' full gx chunk-slices (2 x 7.68KB) into LDS once, so per-step gx
// reads are LDS, not far-L2/HBM — tests the round-7 theory that the ~1200
// cyc/step chain-independent stall is gx load latency. Early exit/start at
// max(lenA,lenB) skips masked steps (mean len=256 -> ~40% fewer steps).
//
// GEMM: 32 t-rows x 128 cols (120 valid), 2x8 micro-tile, fp16 dot2.
template<int K, int LAYER>
__global__ __launch_bounds__(256, 2) void fused2(
    const int cg, const int cs, const int nScan,
    const int* __restrict__ text, const float* __restrict__ emb,
    const __half* __restrict__ Xh,
    const float* __restrict__ Wf, const float* __restrict__ bf,
    const float* __restrict__ Wb, const float* __restrict__ bb,
    __half* __restrict__ gxW, const __half* __restrict__ gxR,
    const float* __restrict__ WhhF, const float* __restrict__ bhhF,
    const float* __restrict__ WhhB, const float* __restrict__ bhhB,
    const int* __restrict__ lens,
    __half* __restrict__ out0,
    float* __restrict__ hcar, float* __restrict__ hlast,
    float* __restrict__ sumb, float* __restrict__ maxb)
{
    __shared__ __align__(16) char smem[62464];
    const int tid = threadIdx.x;

    if ((int)blockIdx.x < nScan) {
        // ============ scan: wave = 2 same-dir chains ============
        const int w = tid >> 6, lane = tid & 63;
        const int pid = blockIdx.x * 4 + w;        // 0..511
        const int dir = pid >> 8;
        const int bA  = (pid & 255) * 2;
        const int bB  = bA + 1;
        const int chunk = dir ? (NC - 1 - cs) : cs;
        const int tbase = chunk * TC;

        // stage gx slices to LDS (480 float4 per chain)
        _Float16* sl   = (_Float16*)smem;
        _Float16* slA  = sl + (size_t)(w * 2 + 0) * 3840;
        _Float16* slB  = sl + (size_t)(w * 2 + 1) * 3840;
        {
            const float4* gA4 = (const float4*)(gxR + ((size_t)(dir*BB + bA) * TC) * GG);
            const float4* gB4 = (const float4*)(gxR + ((size_t)(dir*BB + bB) * TC) * GG);
            float4* dA = (float4*)slA;
            float4* dB = (float4*)slB;
            #pragma unroll
            for (int it = 0; it < 7; ++it) {
                dA[it*64 + lane] = gA4[it*64 + lane];
                dB[it*64 + lane] = gB4[it*64 + lane];
            }
            if (lane < 32) {
                dA[448 + lane] = gA4[448 + lane];
                dB[448 + lane] = gB4[448 + lane];
            }
        }
        __syncthreads();
        if (lane >= HH) return;
        const int j = lane;

        _Float16* hshA = (_Float16*)(smem + 61440) + w * 96;
        _Float16* hshB = hshA + 48;

        const float* Whh = dir ? WhhB : WhhF;
        const float* bhh = dir ? bhhB : bhhF;
        // shared weights (same dir for both chains): 60 VGPRs
        h2_t Wr[HH/2], Wz[HH/2], Wn[HH/2];
        {
            const float4* r4 = (const float4*)(Whh + (size_t)(0*HH + j) * HH);
            const float4* z4 = (const float4*)(Whh + (size_t)(1*HH + j) * HH);
            const float4* n4 = (const float4*)(Whh + (size_t)(2*HH + j) * HH);
            #pragma unroll
            for (int q = 0; q < HH/4; ++q) {
                float4 v;
                v = r4[q]; Wr[2*q] = pack2_(v.x,v.y); Wr[2*q+1] = pack2_(v.z,v.w);
                v = z4[q]; Wz[2*q] = pack2_(v.x,v.y); Wz[2*q+1] = pack2_(v.z,v.w);
                v = n4[q]; Wn[2*q] = pack2_(v.x,v.y); Wn[2*q+1] = pack2_(v.z,v.w);
            }
        }
        const float bR = bhh[j], bZ = bhh[HH + j], bN = bhh[2*HH + j];
        const int lenA = lens[bA], lenB = lens[bB];
        const int maxlen = max(lenA, lenB);

        float hA = (cs == 0) ? 0.0f : hcar[(size_t)(dir*BB + bA) * HH + j];
        float hB = (cs == 0) ? 0.0f : hcar[(size_t)(dir*BB + bB) * HH + j];
        hshA[j] = (_Float16)hA;
        hshB[j] = (_Float16)hB;
        float psA = 0.f, pmA = -3.4e38f, psB = 0.f, pmB = -3.4e38f;

        int sBeg, sEnd;
        if (dir == 0) { sBeg = 0; sEnd = min(TC, max(0, maxlen - tbase)); }
        else          { sBeg = min(TC, max(0, tbase + TC - maxlen)); sEnd = TC; }

        // 1-deep prefetch from LDS slice
        float cgrA=0,cgzA=0,cgnA=0,cgrB=0,cgzB=0,cgnB=0;
        if (sBeg < sEnd) {
            const int so = dir ? (TC - 1 - sBeg) : sBeg;
            cgrA = (float)slA[so*GG + j];
            cgzA = (float)slA[so*GG + HH + j];
            cgnA = (float)slA[so*GG + 2*HH + j];
            cgrB = (float)slB[so*GG + j];
            cgzB = (float)slB[so*GG + HH + j];
            cgnB = (float)slB[so*GG + 2*HH + j];
        }

        const float4* hA4 = (const float4*)hshA;
        const float4* hB4 = (const float4*)hshB;

        for (int s = sBeg; s < sEnd; ++s) {
            const int tOff = dir ? (TC - 1 - s) : s;
            const int t = tbase + tOff;
            float ngrA=0,ngzA=0,ngnA=0,ngrB=0,ngzB=0,ngnB=0;
            if (s + 1 < sEnd) {
                const int so = dir ? (TC - 2 - s) : (s + 1);
                ngrA = (float)slA[so*GG + j];
                ngzA = (float)slA[so*GG + HH + j];
                ngnA = (float)slA[so*GG + 2*HH + j];
                ngrB = (float)slB[so*GG + j];
                ngzB = (float)slB[so*GG + HH + j];
                ngnB = (float)slB[so*GG + 2*HH + j];
            }
            float rA0=bR, rA1=0, zA0=bZ, zA1=0, nA0=bN, nA1=0;
            float rB0=bR, rB1=0, zB0=bZ, zB1=0, nB0=bN, nB1=0;
            #pragma unroll
            for (int q = 0; q < 5; ++q) {
                F4H ua, ub;
                ua.f = hA4[q]; ub.f = hB4[q];
                rA0 = fdot2_(Wr[4*q+0], ua.h[0], rA0);
                zA0 = fdot2_(Wz[4*q+0], ua.h[0], zA0);
                nA0 = fdot2_(Wn[4*q+0], ua.h[0], nA0);
                rB0 = fdot2_(Wr[4*q+0], ub.h[0], rB0);
                zB0 = fdot2_(Wz[4*q+0], ub.h[0], zB0);
                nB0 = fdot2_(Wn[4*q+0], ub.h[0], nB0);
                rA1 = fdot2_(Wr[4*q+1], ua.h[1], rA1);
                zA1 = fdot2_(Wz[4*q+1], ua.h[1], zA1);
                nA1 = fdot2_(Wn[4*q+1], ua.h[1], nA1);
                rB1 = fdot2_(Wr[4*q+1], ub.h[1], rB1);
                zB1 = fdot2_(Wz[4*q+1], ub.h[1], zB1);
                nB1 = fdot2_(Wn[4*q+1], ub.h[1], nB1);
                rA0 = fdot2_(Wr[4*q+2], ua.h[2], rA0);
                zA0 = fdot2_(Wz[4*q+2], ua.h[2], zA0);
                nA0 = fdot2_(Wn[4*q+2], ua.h[2], nA0);
                rB0 = fdot2_(Wr[4*q+2], ub.h[2], rB0);
                zB0 = fdot2_(Wz[4*q+2], ub.h[2], zB0);
                nB0 = fdot2_(Wn[4*q+2], ub.h[2], nB0);
                rA1 = fdot2_(Wr[4*q+3], ua.h[3], rA1);
                zA1 = fdot2_(Wz[4*q+3], ua.h[3], zA1);
                nA1 = fdot2_(Wn[4*q+3], ua.h[3], nA1);
                rB1 = fdot2_(Wr[4*q+3], ub.h[3], rB1);
                zB1 = fdot2_(Wz[4*q+3], ub.h[3], zB1);
                nB1 = fdot2_(Wn[4*q+3], ub.h[3], nB1);
            }
            const float rrA = sigmoid_(cgrA + rA0 + rA1);
            const float rrB = sigmoid_(cgrB + rB0 + rB1);
            const float zzA = sigmoid_(cgzA + zA0 + zA1);
            const float zzB = sigmoid_(cgzB + zB0 + zB1);
            const float nnA = tanhfast_(cgnA + rrA * (nA0 + nA1));
            const float nnB = tanhfast_(cgnB + rrB * (nB0 + nB1));
            const float hnA = (1.0f - zzA) * nnA + zzA * hA;
            const float hnB = (1.0f - zzB) * nnB + zzB * hB;
            const bool vA = (t < lenA), vB = (t < lenB);   // wave-uniform
            hA = vA ? hnA : hA;
            hB = vB ? hnB : hB;
            hshA[j] = (_Float16)hA;    // broadcast for next step
            hshB[j] = (_Float16)hB;
            if (LAYER == 0) {
                if (vA) out0[((size_t)bA*TT + t)*(2*HH) + dir*HH + j] = __float2half(hnA);
                if (vB) out0[((size_t)bB*TT + t)*(2*HH) + dir*HH + j] = __float2half(hnB);
            } else {
                if (vA) { psA += hnA; pmA = fmaxf(pmA, hnA); }
                if (vB) { psB += hnB; pmB = fmaxf(pmB, hnB); }
            }
            cgrA=ngrA; cgzA=ngzA; cgnA=ngnA;
            cgrB=ngrB; cgzB=ngzB; cgnB=ngnB;
        }

        hcar[(size_t)(dir*BB + bA) * HH + j] = hA;
        hcar[(size_t)(dir*BB + bB) * HH + j] = hB;
        if (cs == NC - 1) {
            hlast[((size_t)(LAYER*2 + dir) * BB + bA) * HH + j] = hA;
            hlast[((size_t)(LAYER*2 + dir) * BB + bB) * HH + j] = hB;
        }
        if (LAYER == 1) {
            const size_t pA = (size_t)bA * (2*HH) + dir*HH + j;
            const size_t pB = (size_t)bB * (2*HH) + dir*HH + j;
            if (cs == 0) { sumb[pA] = psA; maxb[pA] = pmA;
                           sumb[pB] = psB; maxb[pB] = pmB; }
            else { sumb[pA] += psA; maxb[pA] = fmaxf(maxb[pA], pmA);
                   sumb[pB] += psB; maxb[pB] = fmaxf(maxb[pB], pmB); }
        }
        return;
    }

    // ================= gemm: 32 rows x 128 cols, fp16 dot2 =================
    constexpr int K2 = K / 2, KQ = K / 4;
    h2_t* Xs2 = (h2_t*)smem;                    // [K2][32]
    h2_t* Ws2 = (h2_t*)(smem + K2 * 32 * 4);    // [K2][128]
    const int gid = blockIdx.x - nScan;
    const int b   = gid & (BB - 1);
    const int dir = gid >> 9;
    const int chunk = dir ? (NC - 1 - cg) : cg;
    const int trow0 = chunk * TC;
    const float* W    = dir ? Wb : Wf;
    const float* bias = dir ? bb : bf;

    if (LAYER == 0) {   // gather emb[text], K=100
        for (int idx = tid; idx < 32 * KQ; idx += 256) {
            const int r = idx & 31, q = idx >> 5;
            const int tok = text[b * TT + trow0 + r];
            const float4 v = ((const float4*)emb)[(size_t)tok * KQ + q];
            Xs2[(2*q+0)*32 + r] = pack2_(v.x, v.y);
            Xs2[(2*q+1)*32 + r] = pack2_(v.z, v.w);
        }
    } else {            // out0 fp16, K=80
        constexpr int KQ8 = K / 8;
        for (int idx = tid; idx < 32 * KQ8; idx += 256) {
            const int r = idx & 31, q = idx >> 5;
            F4H u;
            u.f = ((const float4*)Xh)[((size_t)b * TT + trow0 + r) * KQ8 + q];
            #pragma unroll
            for (int i2 = 0; i2 < 4; ++i2)
                Xs2[(4*q + i2)*32 + r] = u.h[i2];
        }
    }
    for (int idx = tid; idx < 128 * KQ; idx += 256) {
        const int c = idx & 127, q = idx >> 7;
        float4 v = make_float4(0.f, 0.f, 0.f, 0.f);
        if (c < GG) v = ((const float4*)W)[(size_t)c * KQ + q];
        Ws2[(2*q+0)*128 + c] = pack2_(v.x, v.y);
        Ws2[(2*q+1)*128 + c] = pack2_(v.z, v.w);
    }
    __syncthreads();

    const int tx = tid & 15, ty = tid >> 4;  // cols 8tx.., rows 2ty..
    float acc[2][8] = {};
    #pragma unroll 2
    for (int k2 = 0; k2 < K2; ++k2) {
        union { float2 f; h2_t h[2]; } xa;
        F4H w0, w1;
        xa.f = *(const float2*)(Xs2 + k2*32 + (ty << 1));
        w0.f = *(const float4*)(Ws2 + k2*128 + (tx << 3));
        w1.f = *(const float4*)(Ws2 + k2*128 + (tx << 3) + 4);
        #pragma unroll
        for (int i = 0; i < 2; ++i) {
            #pragma unroll
            for (int j2 = 0; j2 < 4; ++j2) {
                acc[i][j2]     = fdot2_(xa.h[i], w0.h[j2], acc[i][j2]);
                acc[i][4 + j2] = fdot2_(xa.h[i], w1.h[j2], acc[i][4 + j2]);
            }
        }
    }
    if (tx < 15) {
        const int c = tx << 3;
        float bv[8];
        #pragma unroll
        for (int j2 = 0; j2 < 8; ++j2) bv[j2] = bias[c + j2];
        #pragma unroll
        for (int i = 0; i < 2; ++i) {
            union { float4 f; __half2 h[4]; } u;
            #pragma unroll
            for (int j2 = 0; j2 < 4; ++j2)
                u.h[j2] = __floats2half2_rn(acc[i][2*j2] + bv[2*j2],
                                            acc[i][2*j2+1] + bv[2*j2+1]);
            *(float4*)(gxW + ((size_t)(dir*BB + b)*TC + (ty<<1) + i) * GG + c) = u.f;
        }
    }
}

// pool_cat = [hb1, hf1, hb0, hf0, avg(80), max(80)] -> fc1(128) -> lrelu -> fc2(1)
__global__ __launch_bounds__(128) void fc_kernel(
    const float* __restrict__ hlast, const float* __restrict__ sumb,
    const float* __restrict__ maxb, const int* __restrict__ lens,
    const float* __restrict__ fc1W, const float* __restrict__ fc1b,
    const float* __restrict__ fc2W, const float* __restrict__ fc2b,
    float* __restrict__ out)
{
    __shared__ float pool[8 * HH];
    __shared__ float red[128];
    const int b = blockIdx.x, tid = threadIdx.x;
    if (tid < HH) {
        pool[tid]        = hlast[(size_t)(3*BB + b) * HH + tid]; // hb1
        pool[HH + tid]   = hlast[(size_t)(2*BB + b) * HH + tid]; // hf1
        pool[2*HH + tid] = hlast[(size_t)(1*BB + b) * HH + tid]; // hb0
        pool[3*HH + tid] = hlast[(size_t)(0*BB + b) * HH + tid]; // hf0
    }
    const float invLen = 1.0f / (float)lens[b];
    if (tid < 2*HH) {
        pool[4*HH + tid] = sumb[(size_t)b * 2*HH + tid] * invLen;
        pool[6*HH + tid] = maxb[(size_t)b * 2*HH + tid];
    }
    __syncthreads();
    float acc = fc1b[tid];
    for (int k = 0; k < 8*HH; ++k)
        acc = fmaf(pool[k], fc1W[(size_t)tid * (8*HH) + k], acc);
    float v = (acc >= 0.0f) ? acc : 0.01f * acc;
    red[tid] = v * fc2W[tid];
    __syncthreads();
    for (int s = 64; s > 0; s >>= 1) {
        if (tid < s) red[tid] += red[tid + s];
        __syncthreads();
    }
    if (tid == 0) out[b] = red[0] + fc2b[0];
}

extern "C" void kernel_launch(void* const* d_in, const int* in_sizes, int n_in,
                              void* d_out, int out_size, void* d_ws, size_t ws_size,
                              hipStream_t stream) {
    const int*   text  = (const int*)d_in[0];
    const int*   lens  = (const int*)d_in[1];
    const float* emb   = (const float*)d_in[2];
    const float* Wih0f = (const float*)d_in[3];
    const float* Whh0f = (const float*)d_in[4];
    const float* bih0f = (const float*)d_in[5];
    const float* bhh0f = (const float*)d_in[6];
    const float* Wih0b = (const float*)d_in[7];
    const float* Whh0b = (const float*)d_in[8];
    const float* bih0b = (const float*)d_in[9];
    const float* bhh0b = (const float*)d_in[10];
    const float* Wih1f = (const float*)d_in[11];
    const float* Whh1f = (const float*)d_in[12];
    const float* bih1f = (const float*)d_in[13];
    const float* bhh1f = (const float*)d_in[14];
    const float* Wih1b = (const float*)d_in[15];
    const float* Whh1b = (const float*)d_in[16];
    const float* bih1b = (const float*)d_in[17];
    const float* bhh1b = (const float*)d_in[18];
    const float* fc1W  = (const float*)d_in[19];
    const float* fc1b  = (const float*)d_in[20];
    const float* fc2W  = (const float*)d_in[21];
    const float* fc2b  = (const float*)d_in[22];
    float* out = (float*)d_out;

    // ws: gx dbuf fp16 2 x [2,B,TC,GG] = 2 x 7.86MB | out0 fp16 41.94MB | small
    char* p = (char*)d_ws;
    const size_t gxN = (size_t)2 * BB * TC * GG * sizeof(__half);
    __half* gxb0  = (__half*)p;  p += gxN;
    __half* gxb1  = (__half*)p;  p += gxN;
    __half* out0  = (__half*)p;  p += (size_t)BB * TT * 2 * HH * sizeof(__half);
    float*  hcar  = (float*)p;   p += (size_t)2 * BB * HH * sizeof(float);
    float*  hlast = (float*)p;   p += (size_t)4 * BB * HH * sizeof(float);
    float*  sumb  = (float*)p;   p += (size_t)BB * 2 * HH * sizeof(float);
    float*  maxb  = (float*)p;
    __half* gxb[2] = { gxb0, gxb1 };

    const int NG = BB * 2;   // 1024 gemm blocks (b x dir)

    // ---- layer 0 ----
    fused2<EE, 0><<<NG, 256, 0, stream>>>(0, 0, 0,
        text, emb, nullptr, Wih0f, bih0f, Wih0b, bih0b,
        gxb[0], gxb[0], Whh0f, bhh0f, Whh0b, bhh0b,
        lens, out0, hcar, hlast, sumb, maxb);
    for (int ci = 1; ci < NC; ++ci)
        fused2<EE, 0><<<NSCAN + NG, 256, 0, stream>>>(ci, ci - 1, NSCAN,
            text, emb, nullptr, Wih0f, bih0f, Wih0b, bih0b,
            gxb[ci & 1], gxb[(ci - 1) & 1], Whh0f, bhh0f, Whh0b, bhh0b,
            lens, out0, hcar, hlast, sumb, maxb);
    fused2<EE, 0><<<NSCAN, 256, 0, stream>>>(0, NC - 1, NSCAN,
        text, emb, nullptr, Wih0f, bih0f, Wih0b, bih0b,
        gxb[0], gxb[(NC - 1) & 1], Whh0f, bhh0f, Whh0b, bhh0b,
        lens, out0, hcar, hlast, sumb, maxb);

    // ---- layer 1 ----
    fused2<2*HH, 1><<<NG, 256, 0, stream>>>(0, 0, 0,
        text, emb, out0, Wih1f, bih1f, Wih1b, bih1b,
        gxb[0], gxb[0], Whh1f, bhh1f, Whh1b, bhh1b,
        lens, out0, hcar, hlast, sumb, maxb);
    for (int ci = 1; ci < NC; ++ci)
        fused2<2*HH, 1><<<NSCAN + NG, 256, 0, stream>>>(ci, ci - 1, NSCAN,
            text, emb, out0, Wih1f, bih1f, Wih1b, bih1b,
            gxb[ci & 1], gxb[(ci - 1) & 1], Whh1f, bhh1f, Whh1b, bhh1b,
            lens, out0, hcar, hlast, sumb, maxb);
    fused2<2*HH, 1><<<NSCAN, 256, 0, stream>>>(0, NC - 1, NSCAN,
        text, emb, out0, Wih1f, bih1f, Wih1b, bih1b,
        gxb[0], gxb[(NC - 1) & 1], Whh1f, bhh1f, Whh1b, bhh1b,
        lens, out0, hcar, hlast, sumb, maxb);

    // ---- head ----
    fc_kernel<<<BB, 128, 0, stream>>>(hlast, sumb, maxb, lens,
        fc1W, fc1b, fc2W, fc2b, out);
}

// Round 9
// 729.892 us; speedup vs baseline: 1.4979x; 1.4979x over previous
//
#include <hip/hip_runtime.h>
#include <hip/hip_fp16.h>

#define BB 512
#define TT 512
#define EE 100
#define HH 40
#define GG 120   // 3*HH
#define TC 64    // timesteps per chunk
#define NC 8     // chunks

typedef _Float16 h2_t __attribute__((ext_vector_type(2)));

__device__ __forceinline__ float fdot2_(h2_t a, h2_t b, float c) {
    return __builtin_amdgcn_fdot2(a, b, c, false);
}
__device__ __forceinline__ h2_t pack2_(float x, float y) {
    h2_t r; r[0] = (_Float16)x; r[1] = (_Float16)y; return r;
}
__device__ __forceinline__ float sigmoid_(float x) {
    return 1.0f / (1.0f + __expf(-x));
}
__device__ __forceinline__ float tanhfast_(float x) {
    float e = __expf(2.0f * x);
    return 1.0f - 2.0f / (e + 1.0f);
}

// Round-9 model (validated against r2/r5/r7/r8 step times): at 1-2 waves/SIMD
// the scan's step time = wave issue-time + dep-chain, serialized; fused GEMM
// waves steal issue slots round-robin (~2-3x tax on the scan). Fixes:
//  (1) s_setprio: scan waves prio 3, GEMM waves prio 0 -> GEMM only gets the
//      scan's stall cycles.
//  (2) length-aware step range [sBeg,sEnd): executed steps are all valid
//      (t < len), so masking logic is gone; skipped steps leave out0/gx
//      garbage that is only ever consumed by other skipped steps (0xAA is
//      finite fp16). ~45% less scan work; freed CUs backfill GEMM blocks.
//  (3) GEMM tiles fully past len return immediately (block-uniform).
// Everything else = round-5 structure: 1 chain/wave, fp16 Whh in 60 VGPRs
// resident under __launch_bounds__(256,2), 1-deep gx prefetch.
template<int K, bool GATHER>
__global__ __launch_bounds__(256, 2) void fused_kernel(
    const int cg, const int cs, const int nScan,
    const int* __restrict__ text, const float* __restrict__ emb,
    const __half* __restrict__ Xh,
    const float* __restrict__ Wf, const float* __restrict__ bf,
    const float* __restrict__ Wb, const float* __restrict__ bb,
    __half* __restrict__ gxW, const __half* __restrict__ gxR,
    const float* __restrict__ WhhF, const float* __restrict__ bhhF,
    const float* __restrict__ WhhB, const float* __restrict__ bhhB,
    const int* __restrict__ lens,
    __half* __restrict__ out0,
    float* __restrict__ hcar, float* __restrict__ hlast,
    float* __restrict__ sumb, float* __restrict__ maxb)
{
    constexpr int K2 = K / 2;
    __shared__ h2_t Xs2[K2 * 64];
    __shared__ h2_t Ws2[K2 * 64];
    __shared__ __align__(16) _Float16 hsh[4][48];
    const int tid = threadIdx.x;

    if ((int)blockIdx.x < nScan) {
        // ============ scan: one wave = one (batch,dir) chain ============
        __builtin_amdgcn_s_setprio(3);
        const int wave = tid >> 6, j = tid & 63;
        if (j >= HH) return;
        const int chain = blockIdx.x * 4 + wave;   // 0..1023
        const int dir = chain >> 9;
        const int b   = chain & (BB - 1);
        const float* Whh = dir ? WhhB : WhhF;
        const float* bhh = dir ? bhhB : bhhF;

        // Whh rows {j,40+j,80+j} packed half2: 60 VGPRs, resident
        h2_t Wr[HH/2], Wz[HH/2], Wn[HH/2];
        {
            const float4* r4 = (const float4*)(Whh + (size_t)(0*HH + j) * HH);
            const float4* z4 = (const float4*)(Whh + (size_t)(1*HH + j) * HH);
            const float4* n4 = (const float4*)(Whh + (size_t)(2*HH + j) * HH);
            #pragma unroll
            for (int q = 0; q < HH/4; ++q) {
                float4 v;
                v = r4[q]; Wr[2*q] = pack2_(v.x,v.y); Wr[2*q+1] = pack2_(v.z,v.w);
                v = z4[q]; Wz[2*q] = pack2_(v.x,v.y); Wz[2*q+1] = pack2_(v.z,v.w);
                v = n4[q]; Wn[2*q] = pack2_(v.x,v.y); Wn[2*q+1] = pack2_(v.z,v.w);
            }
        }
        const float br = bhh[j], bz = bhh[HH + j], bn = bhh[2*HH + j];
        const int len = lens[b];
        const int chunk = dir ? (NC - 1 - cs) : cs;
        const int tbase = chunk * TC;

        // executed step range: all executed steps have t < len
        int sBeg, sEnd;
        if (dir == 0) { sBeg = 0; sEnd = min(TC, max(0, len - tbase)); }
        else          { sBeg = max(0, tbase + TC - len); sEnd = TC; }

        float h = (cs == 0) ? 0.0f : hcar[(size_t)(dir * BB + b) * HH + j];
        hsh[wave][j] = (_Float16)h;
        float psum = 0.0f, pmax = -3.4e38f;
        const size_t gxRow = ((size_t)dir * BB + b) * TC;

        __half rH = __float2half(0.f), zH = rH, nH = rH;
        if (sBeg < sEnd) {
            const int tl0 = dir ? (TC - 1 - sBeg) : sBeg;
            const __half* gp0 = gxR + (gxRow + tl0) * GG;
            rH = gp0[j]; zH = gp0[HH + j]; nH = gp0[2*HH + j];
        }

        const float4* h4 = (const float4*)hsh[wave];
        for (int s = sBeg; s < sEnd; ++s) {
            const int tloc = dir ? (TC - 1 - s) : s;
            const int t = tbase + tloc;
            __half prH = __float2half(0.f), pzH = prH, pnH = prH;
            if (s + 1 < sEnd) {   // prefetch next step's gx
                const int tn = dir ? (TC - 2 - s) : (s + 1);
                const __half* gq = gxR + (gxRow + tn) * GG;
                prH = gq[j]; pzH = gq[HH + j]; pnH = gq[2*HH + j];
            }
            // GEMV: 60 dot2, two partial accumulators per gate
            float r0 = br, r1 = 0.f, z0 = bz, z1 = 0.f, n0 = bn, n1 = 0.f;
            #pragma unroll
            for (int q = 0; q < 5; ++q) {
                union { float4 f; h2_t h[4]; } u;
                u.f = h4[q];
                r0 = fdot2_(Wr[4*q+0], u.h[0], r0);
                z0 = fdot2_(Wz[4*q+0], u.h[0], z0);
                n0 = fdot2_(Wn[4*q+0], u.h[0], n0);
                r1 = fdot2_(Wr[4*q+1], u.h[1], r1);
                z1 = fdot2_(Wz[4*q+1], u.h[1], z1);
                n1 = fdot2_(Wn[4*q+1], u.h[1], n1);
                r0 = fdot2_(Wr[4*q+2], u.h[2], r0);
                z0 = fdot2_(Wz[4*q+2], u.h[2], z0);
                n0 = fdot2_(Wn[4*q+2], u.h[2], n0);
                r1 = fdot2_(Wr[4*q+3], u.h[3], r1);
                z1 = fdot2_(Wz[4*q+3], u.h[3], z1);
                n1 = fdot2_(Wn[4*q+3], u.h[3], n1);
            }
            const float rr = sigmoid_(__half2float(rH) + r0 + r1);
            const float zz = sigmoid_(__half2float(zH) + z0 + z1);
            const float nn = tanhfast_(__half2float(nH) + rr * (n0 + n1));
            const float hn = (1.0f - zz) * nn + zz * h;
            h = hn;                        // all executed steps are valid
            hsh[wave][j] = (_Float16)h;    // broadcast for next step
            if (GATHER) {  // layer 0: materialize out0 fp16 (valid t only)
                out0[((size_t)b * TT + t) * (2*HH) + dir*HH + j] = __float2half(hn);
            } else {       // layer 1: fused pooling (valid t only)
                psum += hn;
                pmax = fmaxf(pmax, hn);
            }
            rH = prH; zH = pzH; nH = pnH;
        }
        hcar[(size_t)(dir * BB + b) * HH + j] = h;
        const int layer = GATHER ? 0 : 1;
        if (cs == NC - 1)
            hlast[((size_t)(layer * 2 + dir) * BB + b) * HH + j] = h;
        if (!GATHER) {
            const size_t pi = (size_t)b * (2*HH) + dir*HH + j;
            if (cs == 0) { sumb[pi] = psum;  maxb[pi] = pmax; }
            else         { sumb[pi] += psum; maxb[pi] = fmaxf(maxb[pi], pmax); }
        }
        return;
    }

    // ================= gemm (fp16 dot2), prio 0 =================
    __builtin_amdgcn_s_setprio(0);
    const int gid = blockIdx.x - nScan;
    const int b   = gid & (BB - 1);
    const int ct  = (gid >> 9) & 1;
    const int dir = gid >> 10;
    const int chunk = dir ? (NC - 1 - cg) : cg;
    const int tbase = chunk * TC;
    if (tbase >= lens[b]) return;   // tile fully past len: gx never read
    const float* W    = dir ? Wb : Wf;
    const float* bias = dir ? bb : bf;
    const int c0 = ct * 64;

    // stage X fp16 k-pair-major: Xs2[k2][r]
    if (GATHER) {
        constexpr int KQ = K / 4;
        for (int idx = tid; idx < 64 * KQ; idx += 256) {
            const int r = idx & 63, q = idx >> 6;
            const int tok = text[b * TT + tbase + r];
            const float4 v = ((const float4*)emb)[(size_t)tok * KQ + q];
            Xs2[(2*q+0)*64 + r] = pack2_(v.x, v.y);
            Xs2[(2*q+1)*64 + r] = pack2_(v.z, v.w);
        }
    } else {
        constexpr int KQ8 = K / 8;
        for (int idx = tid; idx < 64 * KQ8; idx += 256) {
            const int r = idx & 63, q = idx >> 6;
            union { float4 f; h2_t h[4]; } u;
            u.f = ((const float4*)Xh)[((size_t)b * TT + tbase + r) * KQ8 + q];
            #pragma unroll
            for (int i2 = 0; i2 < 4; ++i2)
                Xs2[(4*q + i2)*64 + r] = u.h[i2];
        }
    }
    // stage W fp16 k-pair-major: Ws2[k2][c]
    {
        constexpr int KQ = K / 4;
        for (int idx = tid; idx < 64 * KQ; idx += 256) {
            const int c = idx & 63, q = idx >> 6;
            float4 v = make_float4(0.f,0.f,0.f,0.f);
            if (c0 + c < GG) v = ((const float4*)W)[(size_t)(c0 + c) * KQ + q];
            Ws2[(2*q+0)*64 + c] = pack2_(v.x, v.y);
            Ws2[(2*q+1)*64 + c] = pack2_(v.z, v.w);
        }
    }
    __syncthreads();

    const int tx = tid & 15, ty = tid >> 4;
    float acc[4][4] = {};
    #pragma unroll 2
    for (int k2 = 0; k2 < K2; ++k2) {
        union { float4 f; h2_t h[4]; } xa, wv;
        xa.f = *(const float4*)(Xs2 + k2*64 + (ty << 2));
        wv.f = *(const float4*)(Ws2 + k2*64 + (tx << 2));
        #pragma unroll
        for (int i = 0; i < 4; ++i)
            #pragma unroll
            for (int j2 = 0; j2 < 4; ++j2)
                acc[i][j2] = fdot2_(xa.h[i], wv.h[j2], acc[i][j2]);
    }

    const int c = c0 + (tx << 2);
    if (c < GG) {
        const float b0v = bias[c], b1v = bias[c+1], b2v = bias[c+2], b3v = bias[c+3];
        const size_t rowB = ((size_t)dir * BB + b) * TC;
        #pragma unroll
        for (int i = 0; i < 4; ++i) {
            const int tloc = (ty << 2) + i;
            union { float2 f; __half2 h[2]; } u;
            u.h[0] = __floats2half2_rn(acc[i][0] + b0v, acc[i][1] + b1v);
            u.h[1] = __floats2half2_rn(acc[i][2] + b2v, acc[i][3] + b3v);
            *(float2*)(gxW + (rowB + tloc) * GG + c) = u.f;
        }
    }
}

// pool_cat = [hb1, hf1, hb0, hf0, avg(80), max(80)] -> fc1(128) -> lrelu -> fc2(1)
__global__ __launch_bounds__(128) void fc_kernel(
    const float* __restrict__ hlast, const float* __restrict__ sumb,
    const float* __restrict__ maxb, const int* __restrict__ lens,
    const float* __restrict__ fc1W, const float* __restrict__ fc1b,
    const float* __restrict__ fc2W, const float* __restrict__ fc2b,
    float* __restrict__ out)
{
    __shared__ float pool[8 * HH];
    __shared__ float red[128];
    const int b = blockIdx.x, tid = threadIdx.x;
    if (tid < HH) {
        pool[tid]        = hlast[(size_t)(3*BB + b) * HH + tid]; // hb1
        pool[HH + tid]   = hlast[(size_t)(2*BB + b) * HH + tid]; // hf1
        pool[2*HH + tid] = hlast[(size_t)(1*BB + b) * HH + tid]; // hb0
        pool[3*HH + tid] = hlast[(size_t)(0*BB + b) * HH + tid]; // hf0
    }
    const float invLen = 1.0f / (float)lens[b];
    if (tid < 2*HH) {
        pool[4*HH + tid] = sumb[(size_t)b * 2*HH + tid] * invLen;
        pool[6*HH + tid] = maxb[(size_t)b * 2*HH + tid];
    }
    __syncthreads();
    float acc = fc1b[tid];
    for (int k = 0; k < 8*HH; ++k)
        acc = fmaf(pool[k], fc1W[(size_t)tid * (8*HH) + k], acc);
    float v = (acc >= 0.0f) ? acc : 0.01f * acc;
    red[tid] = v * fc2W[tid];
    __syncthreads();
    for (int s = 64; s > 0; s >>= 1) {
        if (tid < s) red[tid] += red[tid + s];
        __syncthreads();
    }
    if (tid == 0) out[b] = red[0] + fc2b[0];
}

extern "C" void kernel_launch(void* const* d_in, const int* in_sizes, int n_in,
                              void* d_out, int out_size, void* d_ws, size_t ws_size,
                              hipStream_t stream) {
    const int*   text  = (const int*)d_in[0];
    const int*   lens  = (const int*)d_in[1];
    const float* emb   = (const float*)d_in[2];
    const float* Wih0f = (const float*)d_in[3];
    const float* Whh0f = (const float*)d_in[4];
    const float* bih0f = (const float*)d_in[5];
    const float* bhh0f = (const float*)d_in[6];
    const float* Wih0b = (const float*)d_in[7];
    const float* Whh0b = (const float*)d_in[8];
    const float* bih0b = (const float*)d_in[9];
    const float* bhh0b = (const float*)d_in[10];
    const float* Wih1f = (const float*)d_in[11];
    const float* Whh1f = (const float*)d_in[12];
    const float* bih1f = (const float*)d_in[13];
    const float* bhh1f = (const float*)d_in[14];
    const float* Wih1b = (const float*)d_in[15];
    const float* Whh1b = (const float*)d_in[16];
    const float* bih1b = (const float*)d_in[17];
    const float* bhh1b = (const float*)d_in[18];
    const float* fc1W  = (const float*)d_in[19];
    const float* fc1b  = (const float*)d_in[20];
    const float* fc2W  = (const float*)d_in[21];
    const float* fc2b  = (const float*)d_in[22];
    float* out = (float*)d_out;

    // ws: gx double-buffer fp16 (2 x 15.73MB) | out0 fp16 (41.94MB) | small
    char* p = (char*)d_ws;
    const size_t gxB = (size_t)2 * BB * TC * GG * sizeof(__half);
    __half* gxb0  = (__half*)p;  p += gxB;
    __half* gxb1  = (__half*)p;  p += gxB;
    __half* out0  = (__half*)p;  p += (size_t)BB * TT * 2 * HH * sizeof(__half);
    float*  hcar  = (float*)p;   p += (size_t)2 * BB * HH * sizeof(float);
    float*  hlast = (float*)p;   p += (size_t)4 * BB * HH * sizeof(float);
    float*  sumb  = (float*)p;   p += (size_t)BB * 2 * HH * sizeof(float);
    float*  maxb  = (float*)p;
    __half* gxb[2] = { gxb0, gxb1 };

    const int NG = BB * 2 * 2;   // 2048 gemm blocks
    const int NS = 256;          // 1024 chains / 4 waves per block

    // ---- layer 0 ----
    fused_kernel<EE, true><<<NG, 256, 0, stream>>>(0, 0, 0,
        text, emb, nullptr, Wih0f, bih0f, Wih0b, bih0b,
        gxb[0], gxb[0], Whh0f, bhh0f, Whh0b, bhh0b,
        lens, out0, hcar, hlast, sumb, maxb);
    for (int ci = 1; ci < NC; ++ci)
        fused_kernel<EE, true><<<NS + NG, 256, 0, stream>>>(ci, ci - 1, NS,
            text, emb, nullptr, Wih0f, bih0f, Wih0b, bih0b,
            gxb[ci & 1], gxb[(ci - 1) & 1], Whh0f, bhh0f, Whh0b, bhh0b,
            lens, out0, hcar, hlast, sumb, maxb);
    fused_kernel<EE, true><<<NS, 256, 0, stream>>>(0, NC - 1, NS,
        text, emb, nullptr, Wih0f, bih0f, Wih0b, bih0b,
        gxb[0], gxb[(NC - 1) & 1], Whh0f, bhh0f, Whh0b, bhh0b,
        lens, out0, hcar, hlast, sumb, maxb);

    // ---- layer 1 ----
    fused_kernel<2*HH, false><<<NG, 256, 0, stream>>>(0, 0, 0,
        text, emb, out0, Wih1f, bih1f, Wih1b, bih1b,
        gxb[0], gxb[0], Whh1f, bhh1f, Whh1b, bhh1b,
        lens, out0, hcar, hlast, sumb, maxb);
    for (int ci = 1; ci < NC; ++ci)
        fused_kernel<2*HH, false><<<NS + NG, 256, 0, stream>>>(ci, ci - 1, NS,
            text, emb, out0, Wih1f, bih1f, Wih1b, bih1b,
            gxb[ci & 1], gxb[(ci - 1) & 1], Whh1f, bhh1f, Whh1b, bhh1b,
            lens, out0, hcar, hlast, sumb, maxb);
    fused_kernel<2*HH, false><<<NS, 256, 0, stream>>>(0, NC - 1, NS,
        text, emb, out0, Wih1f, bih1f, Wih1b, bih1b,
        gxb[0], gxb[(NC - 1) & 1], Whh1f, bhh1f, Whh1b, bhh1b,
        lens, out0, hcar, hlast, sumb, maxb);

    // ---- head ----
    fc_kernel<<<BB, 128, 0, stream>>>(hlast, sumb, maxb, lens,
        fc1W, fc1b, fc2W, fc2b, out);
}